// Round 1
// baseline (273.261 us; speedup 1.0000x reference)
//
#include <hip/hip_runtime.h>

#define LL 2
#define NP 1024        // N
#define BB 8
#define FF 128
#define HH 256
#define NE (NP*NP)     // 1M edges
#define KT 64

// ---------------- prep: pack edge-MLP coefficients + transpose Wfc ----------------
__global__ __launch_bounds__(256) void prep_kernel(
    const float* __restrict__ W1, const float* __restrict__ b1,
    const float* __restrict__ W2, const float* __restrict__ Wfc,
    float4* __restrict__ pk, float* __restrict__ sw2, float* __restrict__ wt)
{
  __shared__ float red[256];
  int tid = threadIdx.x;
  for (int l = 0; l < LL; ++l) {
    int k = tid;  // H == 256 == blockDim
    float wx = W1[(l*HH + k)*2 + 0];
    float wy = W1[(l*HH + k)*2 + 1];
    float bb = b1[l*HH + k];
    float w2 = W2[l*HH + k];
    // fold log2e so inner loop uses raw v_exp_f32 (exp2)
    pk[l*HH + k] = make_float4(wx*1.44269504f, wy*1.44269504f, bb*1.44269504f, w2);
    red[tid] = w2;
    __syncthreads();
    for (int s = 128; s > 0; s >>= 1) {
      if (tid < s) red[tid] += red[tid+s];
      __syncthreads();
    }
    if (tid == 0) sw2[l] = red[0];
    __syncthreads();
    // WfcT[l][f][g] = Wfc[l][g][f]  (coalesced reads in fx kernel)
    for (int i = tid; i < FF*FF; i += 256) {
      int g = i >> 7, f = i & 127;
      wt[l*FF*FF + f*FF + g] = Wfc[l*FF*FF + g*FF + f];
    }
    __syncthreads();
  }
}

// ---------------- edge MLP: a[l][n][m], both layers per thread ----------------
__global__ __launch_bounds__(256) void edge_mlp_kernel(
    const float2* __restrict__ adj, const float4* __restrict__ pk,
    const float* __restrict__ sw2, const float* __restrict__ b2,
    float* __restrict__ a_out)
{
  int e = blockIdx.x * 256 + threadIdx.x;
  float2 dt = adj[e];
  float mask = (dt.x > 0.0f) ? 1.0f : 0.0f;
  for (int l = 0; l < LL; ++l) {
    const float4* p = pk + l*HH;   // wave-uniform -> s_load
    float accp = 0.f, acce = 0.f;
    #pragma unroll 8
    for (int k = 0; k < HH; ++k) {
      float4 c = p[k];
      float z2 = fmaf(dt.x, c.x, fmaf(dt.y, c.y, c.z));   // z*log2e
      accp = fmaf(c.w, fmaxf(z2, 0.f), accp);             // w2 * relu(z)*log2e
      acce = fmaf(c.w, __builtin_amdgcn_exp2f(fminf(z2, 0.f)), acce); // w2*exp(min(z,0))
    }
    // elu(z) = max(z,0) + exp(min(z,0)) - 1
    float s = fmaf(0.69314718f, accp, acce) - sw2[l] + b2[l];
    float ax = fabsf(s);
    float e2 = __builtin_amdgcn_exp2f(-2.88539008f * ax); // exp(-2|s|)
    float r = (1.f - e2) * __builtin_amdgcn_rcpf(1.f + e2);
    float t = (s >= 0.f) ? r : -r;                        // tanh(s)
    a_out[(size_t)l*NE + e] = mask * t;
  }
}

// ---------------- fx2[m][b][g] = sum_f x[b][m][f] * Wfc[g][f] ----------------
__global__ __launch_bounds__(256) void fx_kernel(
    const float* __restrict__ x, const float* __restrict__ wt,
    float* __restrict__ fx2)
{
  __shared__ float xs[BB][FF];
  int m = blockIdx.x;
  for (int i = threadIdx.x; i < BB*FF; i += 256) {
    int b = i >> 7, f = i & 127;
    xs[b][f] = x[((size_t)b*NP + m)*FF + f];
  }
  __syncthreads();
  int g  = threadIdx.x & 127;
  int bh = threadIdx.x >> 7;   // 0/1 -> batches [0..3] / [4..7]
  float acc0=0.f, acc1=0.f, acc2=0.f, acc3=0.f;
  #pragma unroll 4
  for (int f = 0; f < FF; ++f) {
    float w = wt[f*FF + g];    // coalesced; wt is L2-resident (64KB)
    acc0 = fmaf(xs[bh*4+0][f], w, acc0);
    acc1 = fmaf(xs[bh*4+1][f], w, acc1);
    acc2 = fmaf(xs[bh*4+2][f], w, acc2);
    acc3 = fmaf(xs[bh*4+3][f], w, acc3);
  }
  size_t base = (size_t)m*(BB*FF) + (size_t)(bh*4)*FF + g;
  fx2[base + 0*FF] = acc0;
  fx2[base + 1*FF] = acc1;
  fx2[base + 2*FF] = acc2;
  fx2[base + 3*FF] = acc3;
}

// ---------------- agg: y[b][n][f] = x + bias + sum_m a[n][m]*fx2[m][b*F+f] ----------------
__global__ __launch_bounds__(256) void agg_kernel(
    const float* __restrict__ a, const float* __restrict__ fx2,
    const float* __restrict__ xin, const float* __restrict__ bias_l,
    float* __restrict__ y)
{
  __shared__ float aT[KT][68];   // padded: conflict-free b128 reads
  __shared__ float fxs[KT][64];
  int bx = blockIdx.x & 15;      // j-tile (j = b*128+f)
  int by = blockIdx.x >> 4;      // n-tile
  int n0 = by*64, j0 = bx*64;
  int tid = threadIdx.x;
  int tx = tid & 15, ty = tid >> 4;
  float acc[4][4] = {};
  for (int m0 = 0; m0 < NP; m0 += KT) {
    __syncthreads();
    #pragma unroll
    for (int u = 0; u < 4; ++u) {
      int idx = u*256 + tid;
      int r = idx >> 4;          // 0..63
      int c = (idx & 15)*4;      // 0..60
      float4 v = *(const float4*)&a[(size_t)(n0+r)*NP + m0 + c];
      aT[c+0][r] = v.x; aT[c+1][r] = v.y; aT[c+2][r] = v.z; aT[c+3][r] = v.w;
      *(float4*)&fxs[r][c] = *(const float4*)&fx2[(size_t)(m0+r)*(BB*FF) + j0 + c];
    }
    __syncthreads();
    #pragma unroll 8
    for (int k = 0; k < KT; ++k) {
      float4 av = *(const float4*)&aT[k][ty*4];
      float4 fv = *(const float4*)&fxs[k][tx*4];
      float avv[4] = {av.x, av.y, av.z, av.w};
      float fvv[4] = {fv.x, fv.y, fv.z, fv.w};
      #pragma unroll
      for (int i = 0; i < 4; ++i)
        #pragma unroll
        for (int j = 0; j < 4; ++j)
          acc[i][j] = fmaf(avv[i], fvv[j], acc[i][j]);
    }
  }
  int bb = j0 >> 7;
  int f0 = (j0 & 127) + tx*4;
  float4 bv = *(const float4*)&bias_l[f0];
  #pragma unroll
  for (int i = 0; i < 4; ++i) {
    int n = n0 + ty*4 + i;
    size_t base = ((size_t)bb*NP + n)*FF + f0;
    float4 xv = *(const float4*)&xin[base];
    float4 o;
    o.x = acc[i][0] + xv.x + bv.x;
    o.y = acc[i][1] + xv.y + bv.y;
    o.z = acc[i][2] + xv.z + bv.z;
    o.w = acc[i][3] + xv.w + bv.w;
    *(float4*)&y[base] = o;
  }
}

// ---------------- LayerNorm over F=128, one wave per row ----------------
__global__ __launch_bounds__(256) void ln_kernel(
    const float* __restrict__ y, const float* __restrict__ gamma,
    const float* __restrict__ beta, float* __restrict__ out)
{
  int row  = blockIdx.x*4 + (threadIdx.x >> 6);
  int lane = threadIdx.x & 63;
  const float* yr = y + (size_t)row*FF;
  float2 v = *(const float2*)&yr[lane*2];
  float s  = v.x + v.y;
  float ss = fmaf(v.x, v.x, v.y*v.y);
  #pragma unroll
  for (int o = 32; o > 0; o >>= 1) {
    s  += __shfl_xor(s, o);
    ss += __shfl_xor(ss, o);
  }
  float mean = s * (1.f/FF);
  float var  = ss * (1.f/FF) - mean*mean;
  float inv  = __builtin_amdgcn_rsqf(var + 1e-5f);
  int f = lane*2;
  float2 g2 = *(const float2*)&gamma[f];
  float2 bt = *(const float2*)&beta[f];
  float2 o2;
  o2.x = (v.x - mean)*inv*g2.x + bt.x;
  o2.y = (v.y - mean)*inv*g2.y + bt.y;
  *(float2*)&out[(size_t)row*FF + f] = o2;
}

extern "C" void kernel_launch(void* const* d_in, const int* in_sizes, int n_in,
                              void* d_out, int out_size, void* d_ws, size_t ws_size,
                              hipStream_t stream)
{
  const float* x     = (const float*)d_in[0];
  const float* adj   = (const float*)d_in[1];
  const float* W1    = (const float*)d_in[2];
  const float* b1    = (const float*)d_in[3];
  const float* W2    = (const float*)d_in[4];
  const float* b2    = (const float*)d_in[5];
  const float* Wfc   = (const float*)d_in[6];
  const float* bias  = (const float*)d_in[7];
  const float* gamma = (const float*)d_in[8];
  const float* beta  = (const float*)d_in[9];

  float* ws = (float*)d_ws;
  // ws layout (floats): a[2][1024][1024] | pk[2][256]f4 | sw2 | WfcT[2][128][128] | fx2 | y | xmid
  float*  a_buf = ws + 0;                  // 2,097,152
  float4* pk    = (float4*)(ws + 2097152); // 2,048
  float*  sw2   = ws + 2099200;            // 2 (+pad)
  float*  wt    = ws + 2099216;            // 32,768
  float*  fx2   = ws + 2131984;            // 1,048,576
  float*  ybuf  = ws + 3180560;            // 1,048,576
  float*  xmid  = ws + 4229136;            // 1,048,576  (end ~21.1 MB)

  prep_kernel<<<1, 256, 0, stream>>>(W1, b1, W2, Wfc, pk, sw2, wt);
  edge_mlp_kernel<<<NE/256, 256, 0, stream>>>((const float2*)adj, pk, sw2, b2, a_buf);

  const float* xin = x;
  for (int l = 0; l < LL; ++l) {
    fx_kernel<<<NP, 256, 0, stream>>>(xin, wt + l*FF*FF, fx2);
    agg_kernel<<<256, 256, 0, stream>>>(a_buf + (size_t)l*NE, fx2, xin, bias + l*FF, ybuf);
    float* xout = (l == 0) ? xmid : (float*)d_out;
    ln_kernel<<<BB*NP/4, 256, 0, stream>>>(ybuf, gamma + l*FF, beta + l*FF, xout);
    xin = xmid;
  }
}

// Round 2
// 95.519 us; speedup vs baseline: 2.8608x; 2.8608x over previous
//
#include <hip/hip_runtime.h>

#define LL 2
#define NP 1024
#define BB 8
#define FF 128
#define HH 256
#define NE (NP*NP)
#define GT 128              // table grid
#define TPTS ((GT+1)*(GT+1))   // 16641
#define TAB_STRIDE 16768

typedef __attribute__((ext_vector_type(4))) float f32x4;
typedef __attribute__((ext_vector_type(8))) short bf16x8;

__device__ __forceinline__ ushort f2bf(float f) {
  unsigned int u = __float_as_uint(f);
  return (ushort)((u + 0x7FFF + ((u >> 16) & 1)) >> 16);
}

// ---------------- prep: pack edge-MLP coeffs, Wfc -> bf16 ----------------
__global__ __launch_bounds__(256) void prep_kernel(
    const float* __restrict__ W1, const float* __restrict__ b1,
    const float* __restrict__ W2, const float* __restrict__ Wfc,
    float4* __restrict__ pk, float* __restrict__ sw2, ushort* __restrict__ wfcbf)
{
  __shared__ float red[256];
  int tid = threadIdx.x;
  for (int l = 0; l < LL; ++l) {
    int k = tid;
    float wx = W1[(l*HH + k)*2 + 0];
    float wy = W1[(l*HH + k)*2 + 1];
    float bb = b1[l*HH + k];
    float w2 = W2[l*HH + k];
    pk[l*HH + k] = make_float4(wx*1.44269504f, wy*1.44269504f, bb*1.44269504f, w2);
    red[tid] = w2;
    __syncthreads();
    for (int s = 128; s > 0; s >>= 1) {
      if (tid < s) red[tid] += red[tid+s];
      __syncthreads();
    }
    if (tid == 0) sw2[l] = red[0];
    __syncthreads();
  }
  for (int i = tid; i < LL*FF*FF; i += 256) wfcbf[i] = f2bf(Wfc[i]);
}

// ---------------- table: tab[l][i][j] = tanh(s(i/GT, j/GT)) ----------------
__global__ __launch_bounds__(256) void table_kernel(
    const float4* __restrict__ pk, const float* __restrict__ sw2,
    const float* __restrict__ b2, float* __restrict__ tab)
{
  int p = blockIdx.x*256 + threadIdx.x;
  if (p >= TPTS) return;
  int l = blockIdx.y;
  int i = p / (GT+1), j = p % (GT+1);
  float d = i * (1.0f/GT), t = j * (1.0f/GT);
  const float4* pc = pk + l*HH;
  float accp = 0.f, acce = 0.f;
  #pragma unroll 8
  for (int k = 0; k < HH; ++k) {
    float4 c = pc[k];
    float z2 = fmaf(d, c.x, fmaf(t, c.y, c.z));
    accp = fmaf(c.w, fmaxf(z2, 0.f), accp);
    acce = fmaf(c.w, __builtin_amdgcn_exp2f(fminf(z2, 0.f)), acce);
  }
  float s = fmaf(0.69314718f, accp, acce) - sw2[l] + b2[l];
  float ax = fabsf(s);
  float e2 = __builtin_amdgcn_exp2f(-2.88539008f * ax);
  float r = (1.f - e2) * __builtin_amdgcn_rcpf(1.f + e2);
  tab[l*TAB_STRIDE + p] = (s >= 0.f) ? r : -r;
}

// ---------------- edge lookup: bilinear, 2 edges/thread, bf16 out ----------------
__device__ __forceinline__ float blerp(const float* __restrict__ T, float d, float t) {
  float u = d * (float)GT, v = t * (float)GT;
  int iu = (int)u; iu = min(iu, GT-1);
  int iv = (int)v; iv = min(iv, GT-1);
  float fu = u - iu, fv = v - iv;
  const float* p0 = T + iu*(GT+1) + iv;
  float t00 = p0[0], t01 = p0[1], t10 = p0[GT+1], t11 = p0[GT+2];
  float a = t00 + fv*(t01 - t00);
  float b = t10 + fv*(t11 - t10);
  float r = a + fu*(b - a);
  return (d > 0.f) ? r : 0.f;
}

__global__ __launch_bounds__(256) void edge_lookup_kernel(
    const float4* __restrict__ adj2, const float* __restrict__ tab,
    ushort* __restrict__ a_bf)
{
  int e2 = blockIdx.x*256 + threadIdx.x;   // edges 2*e2, 2*e2+1
  float4 v = adj2[e2];
  #pragma unroll
  for (int l = 0; l < LL; ++l) {
    const float* T = tab + l*TAB_STRIDE;
    ushort r0 = f2bf(blerp(T, v.x, v.y));
    ushort r1 = f2bf(blerp(T, v.z, v.w));
    ushort2 o; o.x = r0; o.y = r1;
    *(ushort2*)&a_bf[(size_t)l*NE + 2*e2] = o;
  }
}

// ---------------- x (f32) -> bf16 ----------------
__global__ __launch_bounds__(256) void cvt_kernel(
    const float* __restrict__ x, ushort* __restrict__ xb)
{
  int i = (blockIdx.x*256 + threadIdx.x)*8;
  float4 a = *(const float4*)(x+i), b = *(const float4*)(x+i+4);
  uint4 o;
  o.x = f2bf(a.x) | ((unsigned)f2bf(a.y) << 16);
  o.y = f2bf(a.z) | ((unsigned)f2bf(a.w) << 16);
  o.z = f2bf(b.x) | ((unsigned)f2bf(b.y) << 16);
  o.w = f2bf(b.z) | ((unsigned)f2bf(b.w) << 16);
  *(uint4*)(xb+i) = o;
}

// ---------------- 64x64-tile bf16 MFMA GEMM, B^T form, double-buffered ----------------
// C[r][j] = sum_k A[r][k] * B[j][k]   (A: M x K row-major, B: N x K row-major)
__device__ __forceinline__ void stage64(const ushort* __restrict__ srcrow0, int stride, int k0,
                                        ushort* dst, int w, int lane)
{
  #pragma unroll
  for (int u = 0; u < 2; ++u) {
    int o = (u*4 + w)*1024 + lane*16;          // byte offset in 8KB tile
    int r = o >> 7;                            // row 0..63
    int c = (o & 127) ^ ((r & 7) << 4);        // unswizzled source col-byte
    const ushort* src = srcrow0 + (size_t)r*stride + k0 + (c >> 1);
    __builtin_amdgcn_global_load_lds(
        (const __attribute__((address_space(1))) unsigned int*)(const void*)src,
        (__attribute__((address_space(3))) unsigned int*)(void*)(dst + (u*4+w)*512),
        16, 0, 0);
  }
}

__device__ __forceinline__ void compute64(const ushort* sAc, const ushort* sBc,
    int wr, int wc, int lane, f32x4 acc[2][2])
{
  bf16x8 af[2][2], bg[2][2];
  int kb = (lane >> 4) * 16;   // byte offset of this lane's 8 k-elems
  #pragma unroll
  for (int mi = 0; mi < 2; ++mi)
    #pragma unroll
    for (int ks = 0; ks < 2; ++ks) {
      int rA = wr*32 + mi*16 + (lane & 15);
      int off = (rA*128 + ks*64 + kb) ^ ((rA & 7) << 4);
      af[mi][ks] = *(const bf16x8*)((const char*)sAc + off);
    }
  #pragma unroll
  for (int nj = 0; nj < 2; ++nj)
    #pragma unroll
    for (int ks = 0; ks < 2; ++ks) {
      int rB = wc*32 + nj*16 + (lane & 15);
      int off = (rB*128 + ks*64 + kb) ^ ((rB & 7) << 4);
      bg[nj][ks] = *(const bf16x8*)((const char*)sBc + off);
    }
  #pragma unroll
  for (int mi = 0; mi < 2; ++mi)
    #pragma unroll
    for (int nj = 0; nj < 2; ++nj)
      #pragma unroll
      for (int ks = 0; ks < 2; ++ks)
        acc[mi][nj] = __builtin_amdgcn_mfma_f32_16x16x32_bf16(
            af[mi][ks], bg[nj][ks], acc[mi][nj], 0, 0, 0);
}

// EPI=0: fx epilogue  (M=g 128, N=bm 8192) -> fxT[(b*128+g)][m] bf16
// EPI=1: agg epilogue (M=n 1024, N=j 1024) -> y = acc + x + bias (f32)
template<int KTOT, int JSHIFT, int EPI>
__global__ __launch_bounds__(256) void gemm_bt_kernel(
    const ushort* __restrict__ A, int lda,
    const ushort* __restrict__ B, int ldb,
    const float* __restrict__ xin, const float* __restrict__ bias_l,
    float* __restrict__ yout, ushort* __restrict__ fxT)
{
  __shared__ __align__(16) ushort sA[2][4096];
  __shared__ __align__(16) ushort sB[2][4096];
  int tid = threadIdx.x;
  int w = tid >> 6, lane = tid & 63;
  int tm = blockIdx.x >> JSHIFT;
  int tj = blockIdx.x & ((1 << JSHIFT) - 1);
  int r0 = tm*64, j0 = tj*64;
  const ushort* Ab = A + (size_t)r0*lda;
  const ushort* Bb = B + (size_t)j0*ldb;
  int wr = w >> 1, wc = w & 1;
  f32x4 acc[2][2] = {};

  stage64(Ab, lda, 0, &sA[0][0], w, lane);
  stage64(Bb, ldb, 0, &sB[0][0], w, lane);
  constexpr int NSTEP = KTOT/64;
  #pragma unroll
  for (int t = 0; t < NSTEP; ++t) {
    int c = t & 1;
    if (t + 1 < NSTEP) {
      stage64(Ab, lda, (t+1)*64, &sA[c^1][0], w, lane);
      stage64(Bb, ldb, (t+1)*64, &sB[c^1][0], w, lane);
      asm volatile("s_waitcnt vmcnt(4)" ::: "memory");
    } else {
      asm volatile("s_waitcnt vmcnt(0)" ::: "memory");
    }
    asm volatile("s_barrier" ::: "memory");
    compute64(&sA[c][0], &sB[c][0], wr, wc, lane, acc);
    asm volatile("s_barrier" ::: "memory");
  }

  int colb = wc*32 + (lane & 15);
  int rowb = wr*32 + ((lane >> 4) << 2);
  #pragma unroll
  for (int mi = 0; mi < 2; ++mi)
    #pragma unroll
    for (int nj = 0; nj < 2; ++nj) {
      if constexpr (EPI == 1) {
        int j = j0 + colb + nj*16;
        int b = j >> 7, f = j & 127;
        float bv = bias_l[f];
        int n = r0 + rowb + mi*16;
        #pragma unroll
        for (int i = 0; i < 4; ++i) {
          size_t off = ((size_t)(b*NP + n + i))*FF + f;
          yout[off] = acc[mi][nj][i] + xin[off] + bv;
        }
      } else {
        int bm = j0 + colb + nj*16;
        int b = bm >> 10, m = bm & 1023;
        int g = r0 + rowb + mi*16;
        #pragma unroll
        for (int i = 0; i < 4; ++i)
          fxT[((size_t)(b*FF + g + i))*NP + m] = f2bf(acc[mi][nj][i]);
      }
    }
}

// ---------------- LayerNorm, writes f32 + bf16 copy ----------------
__global__ __launch_bounds__(256) void ln_kernel(
    const float* __restrict__ y, const float* __restrict__ gamma,
    const float* __restrict__ beta, float* __restrict__ out,
    ushort* __restrict__ outbf)
{
  int row  = blockIdx.x*4 + (threadIdx.x >> 6);
  int lane = threadIdx.x & 63;
  const float* yr = y + (size_t)row*FF;
  float2 v = *(const float2*)&yr[lane*2];
  float s  = v.x + v.y;
  float ss = fmaf(v.x, v.x, v.y*v.y);
  #pragma unroll
  for (int o = 32; o > 0; o >>= 1) {
    s  += __shfl_xor(s, o);
    ss += __shfl_xor(ss, o);
  }
  float mean = s * (1.f/FF);
  float var  = ss * (1.f/FF) - mean*mean;
  float inv  = __builtin_amdgcn_rsqf(var + 1e-5f);
  int f = lane*2;
  float2 g2 = *(const float2*)&gamma[f];
  float2 bt = *(const float2*)&beta[f];
  float2 o2;
  o2.x = (v.x - mean)*inv*g2.x + bt.x;
  o2.y = (v.y - mean)*inv*g2.y + bt.y;
  *(float2*)&out[(size_t)row*FF + f] = o2;
  ((unsigned*)outbf)[(size_t)row*64 + lane] = f2bf(o2.x) | ((unsigned)f2bf(o2.y) << 16);
}

extern "C" void kernel_launch(void* const* d_in, const int* in_sizes, int n_in,
                              void* d_out, int out_size, void* d_ws, size_t ws_size,
                              hipStream_t stream)
{
  const float* x     = (const float*)d_in[0];
  const float* adj   = (const float*)d_in[1];
  const float* W1    = (const float*)d_in[2];
  const float* b1    = (const float*)d_in[3];
  const float* W2    = (const float*)d_in[4];
  const float* b2    = (const float*)d_in[5];
  const float* Wfc   = (const float*)d_in[6];
  const float* bias  = (const float*)d_in[7];
  const float* gamma = (const float*)d_in[8];
  const float* beta  = (const float*)d_in[9];

  float* ws = (float*)d_ws;
  ushort* a_bf  = (ushort*)(ws + 0);        // 2*NE bf16 = 1,048,576 floats
  ushort* fxT   = (ushort*)(ws + 1048576);  // NE bf16 = 524,288 floats
  ushort* xbf   = (ushort*)(ws + 1572864);  // NE bf16 = 524,288 floats
  float4* pk    = (float4*)(ws + 2097152);  // 512 float4
  float*  sw2   = ws + 2099200;             // 2 (+pad)
  ushort* wfcbf = (ushort*)(ws + 2099216);  // 2*16384 bf16 = 16,384 floats
  float*  tab   = ws + 2115600;             // 2*TAB_STRIDE = 33,536
  float*  ybuf  = ws + 2149136;             // 1,048,576
  float*  xmid  = ws + 3197712;             // 1,048,576

  prep_kernel<<<1, 256, 0, stream>>>(W1, b1, W2, Wfc, pk, sw2, wfcbf);
  table_kernel<<<dim3((TPTS+255)/256, LL), 256, 0, stream>>>(pk, sw2, b2, tab);
  edge_lookup_kernel<<<NE/512, 256, 0, stream>>>((const float4*)adj, tab, a_bf);
  cvt_kernel<<<BB*NP*FF/(8*256), 256, 0, stream>>>(x, xbf);

  const float* xin = x;
  for (int l = 0; l < LL; ++l) {
    gemm_bt_kernel<128, 7, 0><<<256, 256, 0, stream>>>(
        wfcbf + l*FF*FF, FF, xbf, FF, nullptr, nullptr, nullptr, fxT);
    gemm_bt_kernel<1024, 4, 1><<<256, 256, 0, stream>>>(
        a_bf + (size_t)l*NE, NP, fxT, NP, xin, bias + l*FF, ybuf, nullptr);
    float* xout = (l == 0) ? xmid : (float*)d_out;
    ln_kernel<<<BB*NP/4, 256, 0, stream>>>(ybuf, gamma + l*FF, beta + l*FF, xout, xbf);
    xin = xmid;
  }
}

// Round 4
// 70.067 us; speedup vs baseline: 3.9000x; 1.3632x over previous
//
#include <hip/hip_runtime.h>

#define LL 2
#define NP 1024
#define BB 8
#define FF 128
#define HH 256
#define NE (NP*NP)
#define GT 128
#define TPTS ((GT+1)*(GT+1))
#define TAB_STRIDE 16768

typedef __attribute__((ext_vector_type(4))) float f32x4;
typedef __attribute__((ext_vector_type(8))) short bf16x8;

__device__ __forceinline__ ushort f2bf(float f) {
  unsigned int u = __float_as_uint(f);
  return (ushort)((u + 0x7FFF + ((u >> 16) & 1)) >> 16);
}

// ---------------- Wfc -> bf16 (parallel, 32 blocks) ----------------
__global__ __launch_bounds__(256) void wcvt_kernel(
    const float* __restrict__ Wfc, ushort* __restrict__ wfcbf)
{
  int i4 = blockIdx.x*256 + threadIdx.x;
  float4 v = *(const float4*)(Wfc + (size_t)i4*4);
  ushort4 o;
  o.x = f2bf(v.x); o.y = f2bf(v.y); o.z = f2bf(v.z); o.w = f2bf(v.w);
  *(ushort4*)(wfcbf + (size_t)i4*4) = o;
}

// ---------------- table: fused coeff prep + tanh-MLP eval ----------------
__global__ __launch_bounds__(256) void table_kernel(
    const float* __restrict__ W1, const float* __restrict__ b1,
    const float* __restrict__ W2, const float* __restrict__ b2,
    float* __restrict__ tab)
{
  __shared__ float4 spk[HH];
  __shared__ float sred[256];
  int tid = threadIdx.x;
  int l = blockIdx.y;
  float wx = W1[(l*HH + tid)*2 + 0];
  float wy = W1[(l*HH + tid)*2 + 1];
  float bb = b1[l*HH + tid];
  float w2 = W2[l*HH + tid];
  spk[tid] = make_float4(wx*1.44269504f, wy*1.44269504f, bb*1.44269504f, w2);
  sred[tid] = w2;
  __syncthreads();
  for (int s = 128; s > 0; s >>= 1) {
    if (tid < s) sred[tid] += sred[tid+s];
    __syncthreads();
  }
  float sw2 = sred[0];
  int p = blockIdx.x*256 + tid;
  if (p >= TPTS) return;
  int i = p / (GT+1), j = p % (GT+1);
  float d = i * (1.0f/GT), t = j * (1.0f/GT);
  float accp = 0.f, acce = 0.f;
  #pragma unroll 8
  for (int k = 0; k < HH; ++k) {
    float4 c = spk[k];
    float z2 = fmaf(d, c.x, fmaf(t, c.y, c.z));
    accp = fmaf(c.w, fmaxf(z2, 0.f), accp);
    acce = fmaf(c.w, __builtin_amdgcn_exp2f(fminf(z2, 0.f)), acce);
  }
  float s = fmaf(0.69314718f, accp, acce) - sw2 + b2[l];
  float ax = fabsf(s);
  float e2 = __builtin_amdgcn_exp2f(-2.88539008f * ax);
  float r = (1.f - e2) * __builtin_amdgcn_rcpf(1.f + e2);
  tab[l*TAB_STRIDE + p] = (s >= 0.f) ? r : -r;
}

// ---------------- edge lookup: bilinear, 2 edges/thread ----------------
__device__ __forceinline__ float blerp(const float* __restrict__ T, float d, float t) {
  float u = d * (float)GT, v = t * (float)GT;
  int iu = (int)u; iu = min(iu, GT-1);
  int iv = (int)v; iv = min(iv, GT-1);
  float fu = u - iu, fv = v - iv;
  const float* p0 = T + iu*(GT+1) + iv;
  float t00 = p0[0], t01 = p0[1], t10 = p0[GT+1], t11 = p0[GT+2];
  float a = t00 + fv*(t01 - t00);
  float b = t10 + fv*(t11 - t10);
  float r = a + fu*(b - a);
  return (d > 0.f) ? r : 0.f;
}

__global__ __launch_bounds__(256) void edge_lookup_kernel(
    const float4* __restrict__ adj2, const float* __restrict__ tab,
    ushort* __restrict__ a_bf)
{
  int e2 = blockIdx.x*256 + threadIdx.x;
  float4 v = adj2[e2];
  #pragma unroll
  for (int l = 0; l < LL; ++l) {
    const float* T = tab + l*TAB_STRIDE;
    ushort2 o;
    o.x = f2bf(blerp(T, v.x, v.y));
    o.y = f2bf(blerp(T, v.z, v.w));
    *(ushort2*)&a_bf[(size_t)l*NE + 2*e2] = o;
  }
}

// ---------------- x[b][m][f] f32 -> xT[(b*128+f)][m] bf16 ----------------
__global__ __launch_bounds__(256) void xt_kernel(
    const float* __restrict__ x, ushort* __restrict__ xT)
{
  __shared__ ushort sT[FF][72];
  int b = blockIdx.x >> 4;
  int m0 = (blockIdx.x & 15) * 64;
  int t = threadIdx.x;
  int mr = t >> 2;                  // 0..63
  int fc = (t & 3) * 32;
  const float* src = x + ((size_t)b*NP + m0 + mr)*FF + fc;
  #pragma unroll
  for (int i = 0; i < 8; ++i) {
    float4 v = *(const float4*)(src + i*4);
    sT[fc + i*4 + 0][mr] = f2bf(v.x);
    sT[fc + i*4 + 1][mr] = f2bf(v.y);
    sT[fc + i*4 + 2][mr] = f2bf(v.z);
    sT[fc + i*4 + 3][mr] = f2bf(v.w);
  }
  __syncthreads();
  int f = t >> 1, half = t & 1;
  ushort* dst = xT + ((size_t)b*FF + f)*NP + m0 + half*32;
  #pragma unroll
  for (int q = 0; q < 4; ++q)
    *(uint4*)(dst + q*8) = *(const uint4*)&sT[f][half*32 + q*8];
}

// ---------------- staging helpers (linear LDS dest + pre-swizzled source) ----------------
__device__ __forceinline__ void stage64(const ushort* __restrict__ srcrow0, int stride, int k0,
                                        ushort* dst, int w, int lane)
{
  #pragma unroll
  for (int u = 0; u < 2; ++u) {
    int o = (u*4 + w)*1024 + lane*16;
    int r = o >> 7;
    int c = (o & 127) ^ ((r & 7) << 4);
    const ushort* src = srcrow0 + (size_t)r*stride + k0 + (c >> 1);
    __builtin_amdgcn_global_load_lds(
        (const __attribute__((address_space(1))) unsigned int*)(const void*)src,
        (__attribute__((address_space(3))) unsigned int*)(void*)(dst + (u*4+w)*512),
        16, 0, 0);
  }
}

__device__ __forceinline__ void stage32(const ushort* __restrict__ srcrow0, int stride, int k0,
                                        ushort* dst, int w, int lane)
{
  int o = w*1024 + lane*16;
  int r = o >> 7;                  // 0..31
  int c = (o & 127) ^ ((r & 7) << 4);
  const ushort* src = srcrow0 + (size_t)r*stride + k0 + (c >> 1);
  __builtin_amdgcn_global_load_lds(
      (const __attribute__((address_space(1))) unsigned int*)(const void*)src,
      (__attribute__((address_space(3))) unsigned int*)(void*)(dst + w*512),
      16, 0, 0);
}

// ---------------- G1: xa[n][j=(b*128+f)] = sum_m a[n][m] * xT[j][m], bf16 out ----------------
__device__ __forceinline__ void compute64(const ushort* sAc, const ushort* sBc,
    int wr, int wc, int lane, f32x4 acc[2][2])
{
  bf16x8 af[2][2], bg[2][2];
  int kb = (lane >> 4) * 16;
  #pragma unroll
  for (int mi = 0; mi < 2; ++mi)
    #pragma unroll
    for (int ks = 0; ks < 2; ++ks) {
      int rA = wr*32 + mi*16 + (lane & 15);
      int off = (rA*128 + ks*64 + kb) ^ ((rA & 7) << 4);
      af[mi][ks] = *(const bf16x8*)((const char*)sAc + off);
    }
  #pragma unroll
  for (int nj = 0; nj < 2; ++nj)
    #pragma unroll
    for (int ks = 0; ks < 2; ++ks) {
      int rB = wc*32 + nj*16 + (lane & 15);
      int off = (rB*128 + ks*64 + kb) ^ ((rB & 7) << 4);
      bg[nj][ks] = *(const bf16x8*)((const char*)sBc + off);
    }
  #pragma unroll
  for (int mi = 0; mi < 2; ++mi)
    #pragma unroll
    for (int nj = 0; nj < 2; ++nj)
      #pragma unroll
      for (int ks = 0; ks < 2; ++ks)
        acc[mi][nj] = __builtin_amdgcn_mfma_f32_16x16x32_bf16(
            af[mi][ks], bg[nj][ks], acc[mi][nj], 0, 0, 0);
}

__global__ __launch_bounds__(256) void g1_kernel(
    const ushort* __restrict__ A, const ushort* __restrict__ B,
    ushort* __restrict__ C)
{
  __shared__ __align__(16) ushort sA[2][4096];
  __shared__ __align__(16) ushort sB[2][4096];
  int tid = threadIdx.x;
  int w = tid >> 6, lane = tid & 63;
  int tm = blockIdx.x >> 4;
  int tj = blockIdx.x & 15;
  int r0 = tm*64, j0 = tj*64;
  const ushort* Ab = A + (size_t)r0*NP;
  const ushort* Bb = B + (size_t)j0*NP;
  int wr = w >> 1, wc = w & 1;
  f32x4 acc[2][2] = {};

  stage64(Ab, NP, 0, &sA[0][0], w, lane);
  stage64(Bb, NP, 0, &sB[0][0], w, lane);
  #pragma unroll
  for (int t = 0; t < 16; ++t) {
    int c = t & 1;
    if (t + 1 < 16) {
      stage64(Ab, NP, (t+1)*64, &sA[c^1][0], w, lane);
      stage64(Bb, NP, (t+1)*64, &sB[c^1][0], w, lane);
      asm volatile("s_waitcnt vmcnt(4)" ::: "memory");
    } else {
      asm volatile("s_waitcnt vmcnt(0)" ::: "memory");
    }
    asm volatile("s_barrier" ::: "memory");
    compute64(&sA[c][0], &sB[c][0], wr, wc, lane, acc);
    asm volatile("s_barrier" ::: "memory");
  }

  int colb = wc*32 + (lane & 15);
  int rowb = wr*32 + ((lane >> 4) << 2);
  #pragma unroll
  for (int mi = 0; mi < 2; ++mi)
    #pragma unroll
    for (int nj = 0; nj < 2; ++nj) {
      int j = j0 + colb + nj*16;
      #pragma unroll
      for (int i = 0; i < 4; ++i) {
        int n = r0 + rowb + mi*16 + i;
        C[(size_t)n*NP + j] = f2bf(acc[mi][nj][i]);
      }
    }
}

// ---------------- K2: fused fc-GEMM + bias + skip + LayerNorm + dual output ----------------
// xh[n][g] = sum_k xa[n][b*128+k] * Wfc[g][k];  y = xh + xin + bias;  LN over g.
template<bool LAST>
__global__ __launch_bounds__(256) void fc_ln_kernel(
    const ushort* __restrict__ xa, const ushort* __restrict__ wl,
    const float* __restrict__ xin, const float* __restrict__ bias_l,
    const float* __restrict__ gamma_l, const float* __restrict__ beta_l,
    float* __restrict__ out, ushort* __restrict__ xT2)
{
  __shared__ __align__(16) char smem[57856];
  ushort* sXA = (ushort*)smem;                        // 8KB: 2 subtiles [32][64]
  ushort* sW  = (ushort*)(smem + 8192);               // 32KB: 4 subtiles [64][64]
  float (*sY)[132] = (float(*)[132])(smem + 40960);   // [32][132] f32
  float (*sXB)[33] = (float(*)[33])(smem + 8192);     // alias sW (dead after MFMA)

  int b  = blockIdx.x >> 5;
  int n0 = (blockIdx.x & 31) * 32;
  int tid = threadIdx.x, w = tid >> 6, lane = tid & 63;

  // stage xa tile [32 n][128 k] (2 k-subtiles) + Wfc [128 g][128 k] (4 subtiles)
  #pragma unroll
  for (int kh = 0; kh < 2; ++kh)
    stage32(xa + (size_t)n0*NP + b*FF, NP, kh*64, sXA + kh*2048, w, lane);
  #pragma unroll
  for (int gr = 0; gr < 2; ++gr)
    #pragma unroll
    for (int kf = 0; kf < 2; ++kf)
      stage64(wl + gr*64*FF, FF, kf*64, sW + (gr*2+kf)*4096, w, lane);

  // skip-connection + bias loads (overlap with staging)
  int col = lane & 15;
  int rowb = (lane >> 4) * 4;
  float xr[2][2][4];
  float bv[2];
  #pragma unroll
  for (int nj = 0; nj < 2; ++nj) {
    int g = w*32 + nj*16 + col;
    bv[nj] = bias_l[g];
    #pragma unroll
    for (int mi = 0; mi < 2; ++mi)
      #pragma unroll
      for (int i = 0; i < 4; ++i)
        xr[mi][nj][i] = xin[((size_t)b*NP + n0 + mi*16 + rowb + i)*FF + g];
  }
  __syncthreads();

  // MFMA: C[32 n][128 g], K=128
  f32x4 acc[2][2] = {};
  #pragma unroll
  for (int ks = 0; ks < 4; ++ks) {
    bf16x8 af[2], bg[2];
    int inb = (ks & 1)*64 + (lane >> 4)*16;
    #pragma unroll
    for (int mi = 0; mi < 2; ++mi) {
      int r = mi*16 + (lane & 15);
      int off = (r*128 + inb) ^ ((r & 7) << 4);
      af[mi] = *(const bf16x8*)((const char*)(sXA + (ks>>1)*2048) + off);
    }
    #pragma unroll
    for (int nj = 0; nj < 2; ++nj) {
      int gg = w*32 + nj*16 + (lane & 15);
      int gr = gg >> 6, rs = gg & 63;
      int off = (rs*128 + inb) ^ ((rs & 7) << 4);
      bg[nj] = *(const bf16x8*)((const char*)(sW + (gr*2 + (ks>>1))*4096) + off);
    }
    #pragma unroll
    for (int mi = 0; mi < 2; ++mi)
      #pragma unroll
      for (int nj = 0; nj < 2; ++nj)
        acc[mi][nj] = __builtin_amdgcn_mfma_f32_16x16x32_bf16(
            af[mi], bg[nj], acc[mi][nj], 0, 0, 0);
  }

  // y -> LDS
  #pragma unroll
  for (int mi = 0; mi < 2; ++mi)
    #pragma unroll
    for (int nj = 0; nj < 2; ++nj) {
      int g = w*32 + nj*16 + col;
      #pragma unroll
      for (int i = 0; i < 4; ++i)
        sY[mi*16 + rowb + i][g] = acc[mi][nj][i] + xr[mi][nj][i] + bv[nj];
    }
  __syncthreads();

  // LayerNorm: 8 threads per row
  int row = tid >> 3, seg = tid & 7;
  float4 v[4];
  float s = 0.f, ss = 0.f;
  #pragma unroll
  for (int q = 0; q < 4; ++q) {
    v[q] = *(const float4*)&sY[row][seg*16 + q*4];
    s  += v[q].x + v[q].y + v[q].z + v[q].w;
    ss += v[q].x*v[q].x + v[q].y*v[q].y + v[q].z*v[q].z + v[q].w*v[q].w;
  }
  #pragma unroll
  for (int o = 1; o < 8; o <<= 1) {
    s  += __shfl_xor(s, o);
    ss += __shfl_xor(ss, o);
  }
  float mean = s * (1.f/FF);
  float var  = ss * (1.f/FF) - mean*mean;
  float inv  = __builtin_amdgcn_rsqf(var + 1e-5f);
  size_t obase = ((size_t)b*NP + n0 + row)*FF + seg*16;
  float res[16];
  #pragma unroll
  for (int q = 0; q < 4; ++q) {
    float4 g4 = *(const float4*)&gamma_l[seg*16 + q*4];
    float4 b4 = *(const float4*)&beta_l[seg*16 + q*4];
    float4 o4;
    o4.x = (v[q].x - mean)*inv*g4.x + b4.x;
    o4.y = (v[q].y - mean)*inv*g4.y + b4.y;
    o4.z = (v[q].z - mean)*inv*g4.z + b4.z;
    o4.w = (v[q].w - mean)*inv*g4.w + b4.w;
    *(float4*)&out[obase + q*4] = o4;
    res[q*4+0] = o4.x; res[q*4+1] = o4.y; res[q*4+2] = o4.z; res[q*4+3] = o4.w;
  }

  if constexpr (!LAST) {
    // transpose via f32 LDS tile (aliases sW; safe: all sW reads done pre-barrier)
    #pragma unroll
    for (int q = 0; q < 16; ++q)
      sXB[seg*16 + q][row] = res[q];
    __syncthreads();
    int f = tid >> 1, half = tid & 1;
    unsigned w0 = (unsigned)f2bf(sXB[f][half*16+0]) | ((unsigned)f2bf(sXB[f][half*16+1])<<16);
    unsigned w1 = (unsigned)f2bf(sXB[f][half*16+2]) | ((unsigned)f2bf(sXB[f][half*16+3])<<16);
    unsigned w2 = (unsigned)f2bf(sXB[f][half*16+4]) | ((unsigned)f2bf(sXB[f][half*16+5])<<16);
    unsigned w3 = (unsigned)f2bf(sXB[f][half*16+6]) | ((unsigned)f2bf(sXB[f][half*16+7])<<16);
    unsigned w4 = (unsigned)f2bf(sXB[f][half*16+8]) | ((unsigned)f2bf(sXB[f][half*16+9])<<16);
    unsigned w5 = (unsigned)f2bf(sXB[f][half*16+10])| ((unsigned)f2bf(sXB[f][half*16+11])<<16);
    unsigned w6 = (unsigned)f2bf(sXB[f][half*16+12])| ((unsigned)f2bf(sXB[f][half*16+13])<<16);
    unsigned w7 = (unsigned)f2bf(sXB[f][half*16+14])| ((unsigned)f2bf(sXB[f][half*16+15])<<16);
    ushort* dst = xT2 + ((size_t)b*FF + f)*NP + n0 + half*16;
    *(uint4*)(dst)     = make_uint4(w0, w1, w2, w3);
    *(uint4*)(dst + 8) = make_uint4(w4, w5, w6, w7);
  }
}

extern "C" void kernel_launch(void* const* d_in, const int* in_sizes, int n_in,
                              void* d_out, int out_size, void* d_ws, size_t ws_size,
                              hipStream_t stream)
{
  const float* x     = (const float*)d_in[0];
  const float* adj   = (const float*)d_in[1];
  const float* W1    = (const float*)d_in[2];
  const float* b1    = (const float*)d_in[3];
  const float* W2    = (const float*)d_in[4];
  const float* b2    = (const float*)d_in[5];
  const float* Wfc   = (const float*)d_in[6];
  const float* bias  = (const float*)d_in[7];
  const float* gamma = (const float*)d_in[8];
  const float* beta  = (const float*)d_in[9];

  float* ws = (float*)d_ws;
  ushort* a_bf  = (ushort*)(ws + 0);        // 2*NE bf16
  ushort* xT    = (ushort*)(ws + 1048576);  // NE bf16
  ushort* xT2   = (ushort*)(ws + 1572864);  // NE bf16
  ushort* xa    = (ushort*)(ws + 2097152);  // NE bf16
  ushort* wfcbf = (ushort*)(ws + 2621440);  // 32768 bf16
  float*  tab   = ws + 2637824;             // 2*TAB_STRIDE
  float*  xmid  = ws + 2671360;             // NE f32

  wcvt_kernel<<<32, 256, 0, stream>>>(Wfc, wfcbf);
  table_kernel<<<dim3((TPTS+255)/256, LL), 256, 0, stream>>>(W1, b1, W2, b2, tab);
  edge_lookup_kernel<<<NE/512, 256, 0, stream>>>((const float4*)adj, tab, a_bf);
  xt_kernel<<<BB*16, 256, 0, stream>>>(x, xT);

  // layer 0
  g1_kernel<<<256, 256, 0, stream>>>(a_bf, xT, xa);
  fc_ln_kernel<false><<<256, 256, 0, stream>>>(xa, wfcbf, x, bias, gamma, beta, xmid, xT2);
  // layer 1
  g1_kernel<<<256, 256, 0, stream>>>(a_bf + NE, xT2, xa);
  fc_ln_kernel<true><<<256, 256, 0, stream>>>(xa, wfcbf + FF*FF, xmid, bias + FF,
                                              gamma + FF, beta + FF, (float*)d_out, nullptr);
}

// Round 8
// 69.819 us; speedup vs baseline: 3.9138x; 1.0036x over previous
//
#include <hip/hip_runtime.h>

#define LL 2
#define NP 1024
#define BB 8
#define FF 128
#define HH 256
#define NE (NP*NP)
#define GT 128
#define TPTS ((GT+1)*(GT+1))

typedef __attribute__((ext_vector_type(4))) float f32x4;
typedef __attribute__((ext_vector_type(8))) short bf16x8;

__device__ __forceinline__ ushort f2bf(float f) {
  unsigned int u = __float_as_uint(f);
  return (ushort)((u + 0x7FFF + ((u >> 16) & 1)) >> 16);
}

// ---------------- pack: xT transpose (blocks 0..127) + Wfc->bf16 (blocks 128..159) ----------------
__global__ __launch_bounds__(256) void pack_kernel(
    const float* __restrict__ x, const float* __restrict__ Wfc,
    ushort* __restrict__ xT, ushort* __restrict__ wfcbf)
{
  __shared__ ushort sT[FF][72];
  int t = threadIdx.x;
  if (blockIdx.x >= 128) {
    int i4 = (blockIdx.x - 128)*256 + t;
    float4 v = *(const float4*)(Wfc + (size_t)i4*4);
    ushort4 o;
    o.x = f2bf(v.x); o.y = f2bf(v.y); o.z = f2bf(v.z); o.w = f2bf(v.w);
    *(ushort4*)(wfcbf + (size_t)i4*4) = o;
    return;
  }
  int b = blockIdx.x >> 4;
  int m0 = (blockIdx.x & 15) * 64;
  int mr = t >> 2;
  int fc = (t & 3) * 32;
  const float* src = x + ((size_t)b*NP + m0 + mr)*FF + fc;
  #pragma unroll
  for (int i = 0; i < 8; ++i) {
    float4 v = *(const float4*)(src + i*4);
    sT[fc + i*4 + 0][mr] = f2bf(v.x);
    sT[fc + i*4 + 1][mr] = f2bf(v.y);
    sT[fc + i*4 + 2][mr] = f2bf(v.z);
    sT[fc + i*4 + 3][mr] = f2bf(v.w);
  }
  __syncthreads();
  int f = t >> 1, half = t & 1;
  ushort* dst = xT + ((size_t)b*FF + f)*NP + m0 + half*32;
  #pragma unroll
  for (int q = 0; q < 4; ++q)
    *(uint4*)(dst + q*8) = *(const uint4*)&sT[f][half*32 + q*8];
}

// ---------------- table: fused coeff prep + tanh-MLP eval, interleaved [p][l] ----------------
__global__ __launch_bounds__(256) void table_kernel(
    const float* __restrict__ W1, const float* __restrict__ b1,
    const float* __restrict__ W2, const float* __restrict__ b2,
    float* __restrict__ tab)
{
  __shared__ float4 spk[HH];
  __shared__ float sred[256];
  int tid = threadIdx.x;
  int l = blockIdx.y;
  float wx = W1[(l*HH + tid)*2 + 0];
  float wy = W1[(l*HH + tid)*2 + 1];
  float bb = b1[l*HH + tid];
  float w2 = W2[l*HH + tid];
  spk[tid] = make_float4(wx*1.44269504f, wy*1.44269504f, bb*1.44269504f, w2);
  sred[tid] = w2;
  __syncthreads();
  for (int s = 128; s > 0; s >>= 1) {
    if (tid < s) sred[tid] += sred[tid+s];
    __syncthreads();
  }
  float sw2 = sred[0];
  int p = blockIdx.x*256 + tid;
  if (p >= TPTS) return;
  int i = p / (GT+1), j = p % (GT+1);
  float d = i * (1.0f/GT), t = j * (1.0f/GT);
  float accp = 0.f, acce = 0.f;
  #pragma unroll 8
  for (int k = 0; k < HH; ++k) {
    float4 c = spk[k];
    float z2 = fmaf(d, c.x, fmaf(t, c.y, c.z));
    accp = fmaf(c.w, fmaxf(z2, 0.f), accp);
    acce = fmaf(c.w, __builtin_amdgcn_exp2f(fminf(z2, 0.f)), acce);
  }
  float s = fmaf(0.69314718f, accp, acce) - sw2 + b2[l];
  float ax = fabsf(s);
  float e2 = __builtin_amdgcn_exp2f(-2.88539008f * ax);
  float r = (1.f - e2) * __builtin_amdgcn_rcpf(1.f + e2);
  tab[p*2 + l] = (s >= 0.f) ? r : -r;
}

// ---------------- edge lookup: bilinear for both layers at once ----------------
__device__ __forceinline__ void lookup2(const float* __restrict__ tab,
                                        float d, float t, float out[2])
{
  float u = d * (float)GT, vv = t * (float)GT;
  int iu = (int)u; iu = min(iu, GT-1);
  int iv = (int)vv; iv = min(iv, GT-1);
  float fu = u - iu, fv = vv - iv;
  const float* p = tab + (size_t)(iu*(GT+1) + iv)*2;
  float2 t00 = *(const float2*)(p);
  float2 t01 = *(const float2*)(p + 2);
  float2 t10 = *(const float2*)(p + (GT+1)*2);
  float2 t11 = *(const float2*)(p + (GT+2)*2);
  float m = (d > 0.f) ? 1.f : 0.f;
  float a0 = t00.x + fv*(t01.x - t00.x);
  float b0 = t10.x + fv*(t11.x - t10.x);
  out[0] = m * (a0 + fu*(b0 - a0));
  float a1 = t00.y + fv*(t01.y - t00.y);
  float b1v = t10.y + fv*(t11.y - t10.y);
  out[1] = m * (a1 + fu*(b1v - a1));
}

__global__ __launch_bounds__(256) void edge_lookup_kernel(
    const float4* __restrict__ adj2, const float* __restrict__ tab,
    ushort* __restrict__ a_bf)
{
  int e2 = blockIdx.x*256 + threadIdx.x;
  float4 v = adj2[e2];
  float r0[2], r1[2];
  lookup2(tab, v.x, v.y, r0);
  lookup2(tab, v.z, v.w, r1);
  #pragma unroll
  for (int l = 0; l < LL; ++l) {
    ushort2 o;
    o.x = f2bf(r0[l]);
    o.y = f2bf(r1[l]);
    *(ushort2*)&a_bf[(size_t)l*NE + 2*e2] = o;
  }
}

// ---------------- staging helpers (linear LDS dest + pre-swizzled source) ----------------
__device__ __forceinline__ void stage64(const ushort* __restrict__ srcrow0, int stride, int k0,
                                        ushort* dst, int w, int lane)
{
  #pragma unroll
  for (int u = 0; u < 2; ++u) {
    int o = (u*4 + w)*1024 + lane*16;
    int r = o >> 7;
    int c = (o & 127) ^ ((r & 7) << 4);
    const ushort* src = srcrow0 + (size_t)r*stride + k0 + (c >> 1);
    __builtin_amdgcn_global_load_lds(
        (const __attribute__((address_space(1))) unsigned int*)(const void*)src,
        (__attribute__((address_space(3))) unsigned int*)(void*)(dst + (u*4+w)*512),
        16, 0, 0);
  }
}

__device__ __forceinline__ void stage32(const ushort* __restrict__ srcrow0, int stride, int k0,
                                        ushort* dst, int w, int lane)
{
  int o = w*1024 + lane*16;
  int r = o >> 7;                  // 0..31
  int c = (o & 127) ^ ((r & 7) << 4);
  const ushort* src = srcrow0 + (size_t)r*stride + k0 + (c >> 1);
  __builtin_amdgcn_global_load_lds(
      (const __attribute__((address_space(1))) unsigned int*)(const void*)src,
      (__attribute__((address_space(3))) unsigned int*)(void*)(dst + w*512),
      16, 0, 0);
}

// ---------------- G1: xa[n][j] = sum_m a[n][m]*xT[j][m]; 32x64 tile, 512 blocks ----------------
__device__ __forceinline__ void compute32x64(const ushort* sAc, const ushort* sBc,
    int wr, int wc, int lane, f32x4 acc[2])
{
  bf16x8 af[2], bg[2][2];
  int kb = (lane >> 4) * 16;
  #pragma unroll
  for (int ks = 0; ks < 2; ++ks) {
    int rA = wr*16 + (lane & 15);
    int off = (rA*128 + ks*64 + kb) ^ ((rA & 7) << 4);
    af[ks] = *(const bf16x8*)((const char*)sAc + off);
  }
  #pragma unroll
  for (int nj = 0; nj < 2; ++nj)
    #pragma unroll
    for (int ks = 0; ks < 2; ++ks) {
      int rB = wc*32 + nj*16 + (lane & 15);
      int off = (rB*128 + ks*64 + kb) ^ ((rB & 7) << 4);
      bg[nj][ks] = *(const bf16x8*)((const char*)sBc + off);
    }
  #pragma unroll
  for (int nj = 0; nj < 2; ++nj)
    #pragma unroll
    for (int ks = 0; ks < 2; ++ks)
      acc[nj] = __builtin_amdgcn_mfma_f32_16x16x32_bf16(
          af[ks], bg[nj][ks], acc[nj], 0, 0, 0);
}

// Double-buffered but __syncthreads-only: correctness is independent of the
// compiler's vmem scheduling (full vmcnt+lgkm drain at each barrier). The
// stage for t+1 is issued right after the barrier and overlaps compute(t).
__global__ __launch_bounds__(256) void g1_kernel(
    const ushort* __restrict__ A, const ushort* __restrict__ B,
    ushort* __restrict__ C)
{
  __shared__ __align__(16) ushort sA[2][2048];  // [32][64] per buf
  __shared__ __align__(16) ushort sB[2][4096];  // [64][64] per buf
  int tid = threadIdx.x;
  int w = tid >> 6, lane = tid & 63;
  int tm = blockIdx.x >> 4;     // 0..31
  int tj = blockIdx.x & 15;     // 0..15
  int n0 = tm*32, j0 = tj*64;
  const ushort* Ab = A + (size_t)n0*NP;
  const ushort* Bb = B + (size_t)j0*NP;
  int wr = w >> 1, wc = w & 1;
  f32x4 acc[2] = {};

  stage32(Ab, NP, 0, &sA[0][0], w, lane);
  stage64(Bb, NP, 0, &sB[0][0], w, lane);
  #pragma unroll
  for (int t = 0; t < 16; ++t) {
    int c = t & 1;
    // Drains vmcnt(0): buf c fully staged for ALL waves.
    // Drains lgkmcnt(0): all waves' reads of buf c^1 (prev iter) done -> safe to overwrite.
    __syncthreads();
    if (t + 1 < 16) {
      stage32(Ab, NP, (t+1)*64, &sA[c^1][0], w, lane);
      stage64(Bb, NP, (t+1)*64, &sB[c^1][0], w, lane);
    }
    compute32x64(&sA[c][0], &sB[c][0], wr, wc, lane, acc);
  }

  int colb = wc*32 + (lane & 15);
  int rowb = wr*16 + ((lane >> 4) << 2);
  #pragma unroll
  for (int nj = 0; nj < 2; ++nj) {
    int j = j0 + colb + nj*16;
    #pragma unroll
    for (int i = 0; i < 4; ++i) {
      int n = n0 + rowb + i;
      C[(size_t)n*NP + j] = f2bf(acc[nj][i]);
    }
  }
}

// ---------------- K2: fused fc-GEMM + bias + skip + LayerNorm + dual output ----------------
// 16-row blocks, 512 blocks.  xh[n][g] = sum_k xa[n][b*128+k]*Wfc[g][k]; y = xh+xin+bias; LN.
template<bool LAST>
__global__ __launch_bounds__(256) void fc_ln_kernel(
    const ushort* __restrict__ xa, const ushort* __restrict__ wl,
    const float* __restrict__ xin, const float* __restrict__ bias_l,
    const float* __restrict__ gamma_l, const float* __restrict__ beta_l,
    float* __restrict__ out, ushort* __restrict__ xT2)
{
  __shared__ __align__(16) char smem[54016];
  ushort* sXA = (ushort*)smem;                        // 4KB: 2 subtiles [16][64] (2048B each)
  ushort* sW  = (ushort*)(smem + 4096);               // 32KB: 4 subtiles [64][64] (8192B each)
  float (*sY)[132] = (float(*)[132])(smem + 36864);   // [16][132] f32 (8448B)
  float (*sXB)[17] = (float(*)[17])(smem + 45312);    // [128][17] f32 (8704B) — no aliasing

  int b  = blockIdx.x >> 6;          // 0..7
  int n0 = (blockIdx.x & 63) * 16;
  int tid = threadIdx.x, w = tid >> 6, lane = tid & 63;

  // stage xa tile [16 n][128 k]: one 16B load per thread
  {
    int kh = tid >> 7;
    int o  = (tid & 127) * 16;
    int r  = o >> 7;                 // 0..15
    int c  = (o & 127) ^ ((r & 7) << 4);
    const ushort* src = xa + (size_t)(n0 + r)*NP + b*FF + kh*64 + (c >> 1);
    __builtin_amdgcn_global_load_lds(
        (const __attribute__((address_space(1))) unsigned int*)(const void*)src,
        (__attribute__((address_space(3))) unsigned int*)(void*)(sXA + w*512),
        16, 0, 0);
  }
  // stage Wfc [128 g][128 k] (4 subtiles, 8192B stride)
  #pragma unroll
  for (int gr = 0; gr < 2; ++gr)
    #pragma unroll
    for (int kf = 0; kf < 2; ++kf)
      stage64(wl + gr*64*FF, FF, kf*64, sW + (gr*2+kf)*4096, w, lane);

  // skip-connection + bias loads (overlap with staging)
  int col = lane & 15;
  int rowb = (lane >> 4) * 4;
  float xr[2][4];
  float bv[2];
  #pragma unroll
  for (int nj = 0; nj < 2; ++nj) {
    int g = w*32 + nj*16 + col;
    bv[nj] = bias_l[g];
    #pragma unroll
    for (int i = 0; i < 4; ++i)
      xr[nj][i] = xin[((size_t)b*NP + n0 + rowb + i)*FF + g];
  }
  __syncthreads();

  // MFMA: C[16 n][128 g], K=128
  f32x4 acc[2] = {};
  #pragma unroll
  for (int ks = 0; ks < 4; ++ks) {
    int inb = (ks & 1)*64 + (lane >> 4)*16;
    int r = lane & 15;
    int offA = (r*128 + inb) ^ ((r & 7) << 4);
    bf16x8 af = *(const bf16x8*)((const char*)sXA + (ks>>1)*2048 + offA);
    #pragma unroll
    for (int nj = 0; nj < 2; ++nj) {
      int gg = w*32 + nj*16 + (lane & 15);
      int gr = gg >> 6, rs = gg & 63;
      int offB = (rs*128 + inb) ^ ((rs & 7) << 4);
      bf16x8 bg = *(const bf16x8*)((const char*)sW + (gr*2 + (ks>>1))*8192 + offB);
      acc[nj] = __builtin_amdgcn_mfma_f32_16x16x32_bf16(af, bg, acc[nj], 0, 0, 0);
    }
  }

  // y -> LDS
  #pragma unroll
  for (int nj = 0; nj < 2; ++nj) {
    int g = w*32 + nj*16 + col;
    #pragma unroll
    for (int i = 0; i < 4; ++i)
      sY[rowb + i][g] = acc[nj][i] + xr[nj][i] + bv[nj];
  }
  __syncthreads();

  // LayerNorm: 16 threads per row
  int row = tid >> 4, seg = tid & 15;
  float4 v[2];
  float s = 0.f, ss = 0.f;
  #pragma unroll
  for (int q = 0; q < 2; ++q) {
    v[q] = *(const float4*)&sY[row][seg*8 + q*4];
    s  += v[q].x + v[q].y + v[q].z + v[q].w;
    ss += v[q].x*v[q].x + v[q].y*v[q].y + v[q].z*v[q].z + v[q].w*v[q].w;
  }
  #pragma unroll
  for (int o = 1; o < 16; o <<= 1) {
    s  += __shfl_xor(s, o);
    ss += __shfl_xor(ss, o);
  }
  float mean = s * (1.f/FF);
  float var  = ss * (1.f/FF) - mean*mean;
  float inv  = __builtin_amdgcn_rsqf(var + 1e-5f);
  size_t obase = ((size_t)b*NP + n0 + row)*FF + seg*8;
  float res[8];
  #pragma unroll
  for (int q = 0; q < 2; ++q) {
    float4 g4 = *(const float4*)&gamma_l[seg*8 + q*4];
    float4 b4 = *(const float4*)&beta_l[seg*8 + q*4];
    float4 o4;
    o4.x = (v[q].x - mean)*inv*g4.x + b4.x;
    o4.y = (v[q].y - mean)*inv*g4.y + b4.y;
    o4.z = (v[q].z - mean)*inv*g4.z + b4.z;
    o4.w = (v[q].w - mean)*inv*g4.w + b4.w;
    *(float4*)&out[obase + q*4] = o4;
    res[q*4+0] = o4.x; res[q*4+1] = o4.y; res[q*4+2] = o4.z; res[q*4+3] = o4.w;
  }

  if constexpr (!LAST) {
    #pragma unroll
    for (int q = 0; q < 8; ++q)
      sXB[seg*8 + q][row] = res[q];
    __syncthreads();
    int f = tid >> 1, half = tid & 1;
    unsigned w0 = (unsigned)f2bf(sXB[f][half*8+0]) | ((unsigned)f2bf(sXB[f][half*8+1])<<16);
    unsigned w1 = (unsigned)f2bf(sXB[f][half*8+2]) | ((unsigned)f2bf(sXB[f][half*8+3])<<16);
    unsigned w2 = (unsigned)f2bf(sXB[f][half*8+4]) | ((unsigned)f2bf(sXB[f][half*8+5])<<16);
    unsigned w3 = (unsigned)f2bf(sXB[f][half*8+6]) | ((unsigned)f2bf(sXB[f][half*8+7])<<16);
    ushort* dst = xT2 + ((size_t)b*FF + f)*NP + n0 + half*8;
    *(uint4*)(dst) = make_uint4(w0, w1, w2, w3);
  }
}

extern "C" void kernel_launch(void* const* d_in, const int* in_sizes, int n_in,
                              void* d_out, int out_size, void* d_ws, size_t ws_size,
                              hipStream_t stream)
{
  const float* x     = (const float*)d_in[0];
  const float* adj   = (const float*)d_in[1];
  const float* W1    = (const float*)d_in[2];
  const float* b1    = (const float*)d_in[3];
  const float* W2    = (const float*)d_in[4];
  const float* b2    = (const float*)d_in[5];
  const float* Wfc   = (const float*)d_in[6];
  const float* bias  = (const float*)d_in[7];
  const float* gamma = (const float*)d_in[8];
  const float* beta  = (const float*)d_in[9];

  float* ws = (float*)d_ws;
  ushort* a_bf  = (ushort*)(ws + 0);        // 2*NE bf16
  ushort* xT    = (ushort*)(ws + 1048576);  // NE bf16
  ushort* xT2   = (ushort*)(ws + 1572864);  // NE bf16
  ushort* xa    = (ushort*)(ws + 2097152);  // NE bf16
  ushort* wfcbf = (ushort*)(ws + 2621440);  // 32768 bf16
  float*  tab   = ws + 2637824;             // TPTS*2 floats (interleaved [p][l])
  float*  xmid  = ws + 2671360;             // NE f32

  pack_kernel<<<160, 256, 0, stream>>>(x, Wfc, xT, wfcbf);
  table_kernel<<<dim3((TPTS+255)/256, LL), 256, 0, stream>>>(W1, b1, W2, b2, tab);
  edge_lookup_kernel<<<NE/512, 256, 0, stream>>>((const float4*)adj, tab, a_bf);

  // layer 0
  g1_kernel<<<512, 256, 0, stream>>>(a_bf, xT, xa);
  fc_ln_kernel<false><<<512, 256, 0, stream>>>(xa, wfcbf, x, bias, gamma, beta, xmid, xT2);
  // layer 1
  g1_kernel<<<512, 256, 0, stream>>>(a_bf + NE, xT2, xa);
  fc_ln_kernel<true><<<512, 256, 0, stream>>>(xa, wfcbf + FF*FF, xmid, bias + FF,
                                              gamma + FF, beta + FF, (float*)d_out, nullptr);
}

// Round 9
// 54.424 us; speedup vs baseline: 5.0209x; 1.2829x over previous
//
#include <hip/hip_runtime.h>

#define LL 2
#define NP 1024
#define BB 8
#define FF 128
#define HH 256
#define NE (NP*NP)
#define GT 128
#define TPTS ((GT+1)*(GT+1))

typedef __attribute__((ext_vector_type(4))) float f32x4;
typedef __attribute__((ext_vector_type(8))) short bf16x8;

__device__ __forceinline__ ushort f2bf(float f) {
  unsigned int u = __float_as_uint(f);
  return (ushort)((u + 0x7FFF + ((u >> 16) & 1)) >> 16);
}

// ---------------- pre: xT transpose (0..127) + Wfc->bf16 (128..159) + table (160..291) ----------------
__global__ __launch_bounds__(256) void pre_kernel(
    const float* __restrict__ x, const float* __restrict__ Wfc,
    const float* __restrict__ W1, const float* __restrict__ b1,
    const float* __restrict__ W2, const float* __restrict__ b2,
    ushort* __restrict__ xT, ushort* __restrict__ wfcbf, float* __restrict__ tab)
{
  __shared__ __align__(16) char smem[18432];
  int t = threadIdx.x;
  int bid = blockIdx.x;

  if (bid >= 160) {               // ---- table branch ----
    float4* spk = (float4*)smem;              // 256 float4
    float*  sred = (float*)(smem + 4096);     // 256 f32
    int q = bid - 160;
    int l = (q >= 66) ? 1 : 0;
    int pb = q - l*66;
    float wx = W1[(l*HH + t)*2 + 0];
    float wy = W1[(l*HH + t)*2 + 1];
    float bb = b1[l*HH + t];
    float w2 = W2[l*HH + t];
    spk[t] = make_float4(wx*1.44269504f, wy*1.44269504f, bb*1.44269504f, w2);
    sred[t] = w2;
    __syncthreads();
    for (int s = 128; s > 0; s >>= 1) {
      if (t < s) sred[t] += sred[t+s];
      __syncthreads();
    }
    float sw2 = sred[0];
    int p = pb*256 + t;
    if (p >= TPTS) return;
    int i = p / (GT+1), j = p % (GT+1);
    float d = i * (1.0f/GT), tt = j * (1.0f/GT);
    float accp = 0.f, acce = 0.f;
    #pragma unroll 8
    for (int k = 0; k < HH; ++k) {
      float4 c = spk[k];
      float z2 = fmaf(d, c.x, fmaf(tt, c.y, c.z));
      accp = fmaf(c.w, fmaxf(z2, 0.f), accp);
      acce = fmaf(c.w, __builtin_amdgcn_exp2f(fminf(z2, 0.f)), acce);
    }
    float s = fmaf(0.69314718f, accp, acce) - sw2 + b2[l];
    float ax = fabsf(s);
    float e2 = __builtin_amdgcn_exp2f(-2.88539008f * ax);
    float r = (1.f - e2) * __builtin_amdgcn_rcpf(1.f + e2);
    tab[p*2 + l] = (s >= 0.f) ? r : -r;
    return;
  }

  if (bid >= 128) {               // ---- Wfc convert branch ----
    int i4 = (bid - 128)*256 + t;
    float4 v = *(const float4*)(Wfc + (size_t)i4*4);
    ushort4 o;
    o.x = f2bf(v.x); o.y = f2bf(v.y); o.z = f2bf(v.z); o.w = f2bf(v.w);
    *(ushort4*)(wfcbf + (size_t)i4*4) = o;
    return;
  }

  // ---- xT transpose branch ----
  ushort (*sT)[72] = (ushort(*)[72])smem;     // [128][72]
  int b = bid >> 4;
  int m0 = (bid & 15) * 64;
  int mr = t >> 2;
  int fc = (t & 3) * 32;
  const float* src = x + ((size_t)b*NP + m0 + mr)*FF + fc;
  #pragma unroll
  for (int i = 0; i < 8; ++i) {
    float4 v = *(const float4*)(src + i*4);
    sT[fc + i*4 + 0][mr] = f2bf(v.x);
    sT[fc + i*4 + 1][mr] = f2bf(v.y);
    sT[fc + i*4 + 2][mr] = f2bf(v.z);
    sT[fc + i*4 + 3][mr] = f2bf(v.w);
  }
  __syncthreads();
  int f = t >> 1, half = t & 1;
  ushort* dst = xT + ((size_t)b*FF + f)*NP + m0 + half*32;
  #pragma unroll
  for (int q = 0; q < 4; ++q)
    *(uint4*)(dst + q*8) = *(const uint4*)&sT[f][half*32 + q*8];
}

// ---------------- edge lookup: bilinear for both layers at once ----------------
__device__ __forceinline__ void lookup2(const float* __restrict__ tab,
                                        float d, float t, float out[2])
{
  float u = d * (float)GT, vv = t * (float)GT;
  int iu = (int)u; iu = min(iu, GT-1);
  int iv = (int)vv; iv = min(iv, GT-1);
  float fu = u - iu, fv = vv - iv;
  const float* p = tab + (size_t)(iu*(GT+1) + iv)*2;
  float2 t00 = *(const float2*)(p);
  float2 t01 = *(const float2*)(p + 2);
  float2 t10 = *(const float2*)(p + (GT+1)*2);
  float2 t11 = *(const float2*)(p + (GT+2)*2);
  float m = (d > 0.f) ? 1.f : 0.f;
  float a0 = t00.x + fv*(t01.x - t00.x);
  float b0 = t10.x + fv*(t11.x - t10.x);
  out[0] = m * (a0 + fu*(b0 - a0));
  float a1 = t00.y + fv*(t01.y - t00.y);
  float b1v = t10.y + fv*(t11.y - t10.y);
  out[1] = m * (a1 + fu*(b1v - a1));
}

__global__ __launch_bounds__(256) void edge_lookup_kernel(
    const float4* __restrict__ adj2, const float* __restrict__ tab,
    ushort* __restrict__ a_bf)
{
  int e2 = blockIdx.x*256 + threadIdx.x;
  float4 v = adj2[e2];
  float r0[2], r1[2];
  lookup2(tab, v.x, v.y, r0);
  lookup2(tab, v.z, v.w, r1);
  #pragma unroll
  for (int l = 0; l < LL; ++l) {
    ushort2 o;
    o.x = f2bf(r0[l]);
    o.y = f2bf(r1[l]);
    *(ushort2*)&a_bf[(size_t)l*NE + 2*e2] = o;
  }
}

// ---------------- staging helpers (linear LDS dest + pre-swizzled source) ----------------
__device__ __forceinline__ void stage64(const ushort* __restrict__ srcrow0, int stride, int k0,
                                        ushort* dst, int w, int lane)
{
  #pragma unroll
  for (int u = 0; u < 2; ++u) {
    int o = (u*4 + w)*1024 + lane*16;
    int r = o >> 7;
    int c = (o & 127) ^ ((r & 7) << 4);
    const ushort* src = srcrow0 + (size_t)r*stride + k0 + (c >> 1);
    __builtin_amdgcn_global_load_lds(
        (const __attribute__((address_space(1))) unsigned int*)(const void*)src,
        (__attribute__((address_space(3))) unsigned int*)(void*)(dst + (u*4+w)*512),
        16, 0, 0);
  }
}

__device__ __forceinline__ void stage32(const ushort* __restrict__ srcrow0, int stride, int k0,
                                        ushort* dst, int w, int lane)
{
  int o = w*1024 + lane*16;
  int r = o >> 7;                  // 0..31
  int c = (o & 127) ^ ((r & 7) << 4);
  const ushort* src = srcrow0 + (size_t)r*stride + k0 + (c >> 1);
  __builtin_amdgcn_global_load_lds(
      (const __attribute__((address_space(1))) unsigned int*)(const void*)src,
      (__attribute__((address_space(3))) unsigned int*)(void*)(dst + w*512),
      16, 0, 0);
}

// ---------------- G1: xa[n][j] = sum_m a[n][m]*xT[j][m]; 32x64 tile, BK=128, 512 blocks ----------------
// LDS per buf: sA = 2 subtiles [32][64] (4KB each), sB = 2 subtiles [64][64] (8KB each).
__device__ __forceinline__ void compute32x64_bk128(const ushort* sAc, const ushort* sBc,
    int wr, int wc, int lane, f32x4 acc[2])
{
  int kb = (lane >> 4) * 16;
  #pragma unroll
  for (int ks = 0; ks < 4; ++ks) {
    int sub = ks >> 1;
    int inb = (ks & 1)*64 + kb;
    int rA = wr*16 + (lane & 15);
    int offA = (rA*128 + inb) ^ ((rA & 7) << 4);
    bf16x8 af = *(const bf16x8*)((const char*)sAc + sub*4096 + offA);
    #pragma unroll
    for (int nj = 0; nj < 2; ++nj) {
      int rB = wc*32 + nj*16 + (lane & 15);
      int offB = (rB*128 + inb) ^ ((rB & 7) << 4);
      bf16x8 bg = *(const bf16x8*)((const char*)sBc + sub*8192 + offB);
      acc[nj] = __builtin_amdgcn_mfma_f32_16x16x32_bf16(af, bg, acc[nj], 0, 0, 0);
    }
  }
}

// Double-buffered, __syncthreads-only (correctness independent of vmem scheduling).
__global__ __launch_bounds__(256) void g1_kernel(
    const ushort* __restrict__ A, const ushort* __restrict__ B,
    ushort* __restrict__ C)
{
  __shared__ __align__(16) ushort sA[2][4096];  // 2 x (2 subtiles [32][64])  = 16KB
  __shared__ __align__(16) ushort sB[2][8192];  // 2 x (2 subtiles [64][64])  = 32KB
  int tid = threadIdx.x;
  int w = tid >> 6, lane = tid & 63;
  int tm = blockIdx.x >> 4;     // 0..31
  int tj = blockIdx.x & 15;     // 0..15
  int n0 = tm*32, j0 = tj*64;
  const ushort* Ab = A + (size_t)n0*NP;
  const ushort* Bb = B + (size_t)j0*NP;
  int wr = w >> 1, wc = w & 1;
  f32x4 acc[2] = {};

  // prologue: stage tile 0 (k0 = 0)
  stage32(Ab, NP, 0,  &sA[0][0],    w, lane);
  stage32(Ab, NP, 64, &sA[0][2048], w, lane);
  stage64(Bb, NP, 0,  &sB[0][0],    w, lane);
  stage64(Bb, NP, 64, &sB[0][4096], w, lane);
  #pragma unroll
  for (int t = 0; t < 8; ++t) {
    int c = t & 1;
    // Full drain: buf c staged for all waves; prev reads of buf c^1 complete.
    __syncthreads();
    if (t + 1 < 8) {
      int k0 = (t+1)*128;
      stage32(Ab, NP, k0,      &sA[c^1][0],    w, lane);
      stage32(Ab, NP, k0 + 64, &sA[c^1][2048], w, lane);
      stage64(Bb, NP, k0,      &sB[c^1][0],    w, lane);
      stage64(Bb, NP, k0 + 64, &sB[c^1][4096], w, lane);
    }
    compute32x64_bk128(&sA[c][0], &sB[c][0], wr, wc, lane, acc);
  }

  int colb = wc*32 + (lane & 15);
  int rowb = wr*16 + ((lane >> 4) << 2);
  #pragma unroll
  for (int nj = 0; nj < 2; ++nj) {
    int j = j0 + colb + nj*16;
    #pragma unroll
    for (int i = 0; i < 4; ++i) {
      int n = n0 + rowb + i;
      C[(size_t)n*NP + j] = f2bf(acc[nj][i]);
    }
  }
}

// ---------------- K2: fused fc-GEMM + bias + skip + LayerNorm + dual output ----------------
// 16-row blocks, 512 blocks.  xh[n][g] = sum_k xa[n][b*128+k]*Wfc[g][k]; y = xh+xin+bias; LN.
template<bool LAST>
__global__ __launch_bounds__(256) void fc_ln_kernel(
    const ushort* __restrict__ xa, const ushort* __restrict__ wl,
    const float* __restrict__ xin, const float* __restrict__ bias_l,
    const float* __restrict__ gamma_l, const float* __restrict__ beta_l,
    float* __restrict__ out, ushort* __restrict__ xT2)
{
  __shared__ __align__(16) char smem[54016];
  ushort* sXA = (ushort*)smem;                        // 4KB: 2 subtiles [16][64] (2048B each)
  ushort* sW  = (ushort*)(smem + 4096);               // 32KB: 4 subtiles [64][64] (8192B each)
  float (*sY)[132] = (float(*)[132])(smem + 36864);   // [16][132] f32 (8448B)
  float (*sXB)[17] = (float(*)[17])(smem + 45312);    // [128][17] f32 (8704B) — no aliasing

  int b  = blockIdx.x >> 6;          // 0..7
  int n0 = (blockIdx.x & 63) * 16;
  int tid = threadIdx.x, w = tid >> 6, lane = tid & 63;

  // stage xa tile [16 n][128 k]: one 16B load per thread
  {
    int kh = tid >> 7;
    int o  = (tid & 127) * 16;
    int r  = o >> 7;                 // 0..15
    int c  = (o & 127) ^ ((r & 7) << 4);
    const ushort* src = xa + (size_t)(n0 + r)*NP + b*FF + kh*64 + (c >> 1);
    __builtin_amdgcn_global_load_lds(
        (const __attribute__((address_space(1))) unsigned int*)(const void*)src,
        (__attribute__((address_space(3))) unsigned int*)(void*)(sXA + w*512),
        16, 0, 0);
  }
  // stage Wfc [128 g][128 k] (4 subtiles, 8192B stride)
  #pragma unroll
  for (int gr = 0; gr < 2; ++gr)
    #pragma unroll
    for (int kf = 0; kf < 2; ++kf)
      stage64(wl + gr*64*FF, FF, kf*64, sW + (gr*2+kf)*4096, w, lane);

  // skip-connection + bias loads (overlap with staging)
  int col = lane & 15;
  int rowb = (lane >> 4) * 4;
  float xr[2][4];
  float bv[2];
  #pragma unroll
  for (int nj = 0; nj < 2; ++nj) {
    int g = w*32 + nj*16 + col;
    bv[nj] = bias_l[g];
    #pragma unroll
    for (int i = 0; i < 4; ++i)
      xr[nj][i] = xin[((size_t)b*NP + n0 + rowb + i)*FF + g];
  }
  __syncthreads();

  // MFMA: C[16 n][128 g], K=128
  f32x4 acc[2] = {};
  #pragma unroll
  for (int ks = 0; ks < 4; ++ks) {
    int inb = (ks & 1)*64 + (lane >> 4)*16;
    int r = lane & 15;
    int offA = (r*128 + inb) ^ ((r & 7) << 4);
    bf16x8 af = *(const bf16x8*)((const char*)sXA + (ks>>1)*2048 + offA);
    #pragma unroll
    for (int nj = 0; nj < 2; ++nj) {
      int gg = w*32 + nj*16 + (lane & 15);
      int gr = gg >> 6, rs = gg & 63;
      int offB = (rs*128 + inb) ^ ((rs & 7) << 4);
      bf16x8 bg = *(const bf16x8*)((const char*)sW + (gr*2 + (ks>>1))*8192 + offB);
      acc[nj] = __builtin_amdgcn_mfma_f32_16x16x32_bf16(af, bg, acc[nj], 0, 0, 0);
    }
  }

  // y -> LDS
  #pragma unroll
  for (int nj = 0; nj < 2; ++nj) {
    int g = w*32 + nj*16 + col;
    #pragma unroll
    for (int i = 0; i < 4; ++i)
      sY[rowb + i][g] = acc[nj][i] + xr[nj][i] + bv[nj];
  }
  __syncthreads();

  // LayerNorm: 16 threads per row
  int row = tid >> 4, seg = tid & 15;
  float4 v[2];
  float s = 0.f, ss = 0.f;
  #pragma unroll
  for (int q = 0; q < 2; ++q) {
    v[q] = *(const float4*)&sY[row][seg*8 + q*4];
    s  += v[q].x + v[q].y + v[q].z + v[q].w;
    ss += v[q].x*v[q].x + v[q].y*v[q].y + v[q].z*v[q].z + v[q].w*v[q].w;
  }
  #pragma unroll
  for (int o = 1; o < 16; o <<= 1) {
    s  += __shfl_xor(s, o);
    ss += __shfl_xor(ss, o);
  }
  float mean = s * (1.f/FF);
  float var  = ss * (1.f/FF) - mean*mean;
  float inv  = __builtin_amdgcn_rsqf(var + 1e-5f);
  size_t obase = ((size_t)b*NP + n0 + row)*FF + seg*8;
  float res[8];
  #pragma unroll
  for (int q = 0; q < 2; ++q) {
    float4 g4 = *(const float4*)&gamma_l[seg*8 + q*4];
    float4 b4 = *(const float4*)&beta_l[seg*8 + q*4];
    float4 o4;
    o4.x = (v[q].x - mean)*inv*g4.x + b4.x;
    o4.y = (v[q].y - mean)*inv*g4.y + b4.y;
    o4.z = (v[q].z - mean)*inv*g4.z + b4.z;
    o4.w = (v[q].w - mean)*inv*g4.w + b4.w;
    *(float4*)&out[obase + q*4] = o4;
    res[q*4+0] = o4.x; res[q*4+1] = o4.y; res[q*4+2] = o4.z; res[q*4+3] = o4.w;
  }

  if constexpr (!LAST) {
    #pragma unroll
    for (int q = 0; q < 8; ++q)
      sXB[seg*8 + q][row] = res[q];
    __syncthreads();
    int f = tid >> 1, half = tid & 1;
    unsigned w0 = (unsigned)f2bf(sXB[f][half*8+0]) | ((unsigned)f2bf(sXB[f][half*8+1])<<16);
    unsigned w1 = (unsigned)f2bf(sXB[f][half*8+2]) | ((unsigned)f2bf(sXB[f][half*8+3])<<16);
    unsigned w2 = (unsigned)f2bf(sXB[f][half*8+4]) | ((unsigned)f2bf(sXB[f][half*8+5])<<16);
    unsigned w3 = (unsigned)f2bf(sXB[f][half*8+6]) | ((unsigned)f2bf(sXB[f][half*8+7])<<16);
    ushort* dst = xT2 + ((size_t)b*FF + f)*NP + n0 + half*8;
    *(uint4*)(dst) = make_uint4(w0, w1, w2, w3);
  }
}

extern "C" void kernel_launch(void* const* d_in, const int* in_sizes, int n_in,
                              void* d_out, int out_size, void* d_ws, size_t ws_size,
                              hipStream_t stream)
{
  const float* x     = (const float*)d_in[0];
  const float* adj   = (const float*)d_in[1];
  const float* W1    = (const float*)d_in[2];
  const float* b1    = (const float*)d_in[3];
  const float* W2    = (const float*)d_in[4];
  const float* b2    = (const float*)d_in[5];
  const float* Wfc   = (const float*)d_in[6];
  const float* bias  = (const float*)d_in[7];
  const float* gamma = (const float*)d_in[8];
  const float* beta  = (const float*)d_in[9];

  float* ws = (float*)d_ws;
  ushort* a_bf  = (ushort*)(ws + 0);        // 2*NE bf16
  ushort* xT    = (ushort*)(ws + 1048576);  // NE bf16
  ushort* xT2   = (ushort*)(ws + 1572864);  // NE bf16
  ushort* xa    = (ushort*)(ws + 2097152);  // NE bf16
  ushort* wfcbf = (ushort*)(ws + 2621440);  // 32768 bf16
  float*  tab   = ws + 2637824;             // TPTS*2 floats (interleaved [p][l])
  float*  xmid  = ws + 2671360;             // NE f32

  pre_kernel<<<292, 256, 0, stream>>>(x, Wfc, W1, b1, W2, b2, xT, wfcbf, tab);
  edge_lookup_kernel<<<NE/512, 256, 0, stream>>>((const float4*)adj, tab, a_bf);

  // layer 0
  g1_kernel<<<512, 256, 0, stream>>>(a_bf, xT, xa);
  fc_ln_kernel<false><<<512, 256, 0, stream>>>(xa, wfcbf, x, bias, gamma, beta, xmid, xT2);
  // layer 1
  g1_kernel<<<512, 256, 0, stream>>>(a_bf + NE, xT2, xa);
  fc_ln_kernel<true><<<512, 256, 0, stream>>>(xa, wfcbf + FF*FF, xmid, bias + FF,
                                              gamma + FF, beta + FF, (float*)d_out, nullptr);
}